// Round 3
// baseline (369.286 us; speedup 1.0000x reference)
//
#include <hip/hip_runtime.h>
#include <stdint.h>

// TinyMod v3: split pipeline through workspace.
//  K1: x[8192,4096] f32 -> y[b][c][m] bf16 (ws)   (stage1 / fcin)
//  K2: y + W_mods(bf16 ws) -> out f32              (stage2 + stage3 fused)
// Fallback (ws too small): round-2 fused kernel (correct, slower).

#define IDIM  4096
#define ODIM  4096

typedef __attribute__((ext_vector_type(8))) __bf16 bf16x8;
typedef __attribute__((ext_vector_type(4))) float  floatx4;

union BF8 { uint32_t w[4]; unsigned short h[8]; bf16x8 v; };

__device__ __forceinline__ unsigned short f2bf(float f) {
    uint32_t u = __builtin_bit_cast(uint32_t, f);
    u += 0x7fffu + ((u >> 16) & 1u);   // RNE
    return (unsigned short)(u >> 16);
}

// ======================= K1: x -> y =======================
// 512 thr (8 waves), BT=16 rows, grid 512. 8 m-chunks of 16.
// xs[m16][bt16][i32] bf16, double-buffered; pitches: i-row 40, m 656.
//   staging b128 writes start-dw = 8*smp+20*sbt (uniform); A-frag reads
//   start-dw = 20*l15+4*grp (uniform).
#define XP1_BT 40
#define XP1_M  656
#define XS1    (16 * XP1_M)   // 10496 elems = 20992 B per buffer

__global__ __launch_bounds__(512, 6)
void k1_fcin(const float* __restrict__ x,
             const float* __restrict__ W_in,
             const float* __restrict__ b_in,
             unsigned short* __restrict__ y)
{
    __shared__ unsigned short xs[2 * XS1] __attribute__((aligned(16)));

    const int tid  = threadIdx.x;
    const int w    = tid >> 6;           // 0..7
    const int lane = tid & 63;
    const int l15  = lane & 15;
    const int grp  = lane >> 4;
    const int row0 = blockIdx.x * 16;

    const int mq = w & 3, cc = w >> 2;   // wave -> m-quad, c-half
    BF8 winf;
    {
        const float* p = W_in + (l15 + 16*cc) * 32 + grp * 8;   // B[k=i][col=c]
        #pragma unroll
        for (int j = 0; j < 8; j++) winf.h[j] = f2bf(p[j]);
    }
    const float bin = b_in[l15 + 16*cc];

    // staging: thread -> (m=smp, bt=sbt, i-half sih); 16 strided loads/chunk
    const int smp = tid & 15, sbt = (tid >> 4) & 15, sih = tid >> 8;
    const float* xb = x + (row0 + sbt) * IDIM + sih * (16 * 128) + smp;

    float xr[16];
    #pragma unroll
    for (int j = 0; j < 16; j++) xr[j] = xb[j * 128];

    for (int mc = 0; mc < 8; mc++) {
        unsigned short* buf = &xs[(mc & 1) * XS1];
        // staged regs -> xs (two b128 per thread)
        #pragma unroll
        for (int p = 0; p < 2; p++) {
            BF8 t;
            #pragma unroll
            for (int j = 0; j < 8; j++) t.h[j] = f2bf(xr[p*8 + j]);
            uint4 v4; v4.x = t.w[0]; v4.y = t.w[1]; v4.z = t.w[2]; v4.w = t.w[3];
            *(uint4*)&buf[smp*XP1_M + sbt*XP1_BT + sih*16 + p*8] = v4;
        }
        __syncthreads();

        // next chunk's loads (independent; compiler schedules early)
        if (mc < 7) {
            #pragma unroll
            for (int j = 0; j < 16; j++) xr[j] = xb[j*128 + (mc + 1)*16];
        }

        // 4 MFMA: m = mq*4+k; D[row=bt][col=c]
        unsigned short yh[4][4];
        #pragma unroll
        for (int k = 0; k < 4; k++) {
            BF8 a;
            const uint4 av = *(const uint4*)&buf[(mq*4 + k)*XP1_M + l15*XP1_BT + grp*8];
            a.w[0] = av.x; a.w[1] = av.y; a.w[2] = av.z; a.w[3] = av.w;
            floatx4 yv = {0.f, 0.f, 0.f, 0.f};
            yv = __builtin_amdgcn_mfma_f32_16x16x32_bf16(a.v, winf.v, yv, 0, 0, 0);
            #pragma unroll
            for (int r = 0; r < 4; r++) yh[k][r] = f2bf(yv[r] + bin);
        }
        // direct packed y stores: lane -> (bt=grp*4+r, c=l15+16cc), 4 m contiguous
        #pragma unroll
        for (int r = 0; r < 4; r++) {
            uint2 pk;
            pk.x = (uint32_t)yh[0][r] | ((uint32_t)yh[1][r] << 16);
            pk.y = (uint32_t)yh[2][r] | ((uint32_t)yh[3][r] << 16);
            *(uint2*)&y[((row0 + grp*4 + r) * 32 + (l15 + 16*cc)) * 128 + mc*16 + mq*4] = pk;
        }
    }
}

// ======================= K2: y -> out =======================
// 512 thr (8 waves), BT=16 rows, grid 512. 4 n-quarters of 32.
// z acc = 32 regs/thread. wc[n32][bt16][c32] bf16, pitches 36 / 580.
#define WP2_BT 36
#define WP2_N  580
#define WC2    (32 * WP2_N)   // 18560 elems = 37120 B

__global__ __launch_bounds__(512, 4)
void k2_mods_out(const unsigned short* __restrict__ y,
                 const unsigned short* __restrict__ wm16,
                 const float* __restrict__ b_mods,
                 const float* __restrict__ W_out,
                 const float* __restrict__ b_out,
                 float* __restrict__ out)
{
    __shared__ unsigned short wc[WC2] __attribute__((aligned(16)));

    const int tid  = threadIdx.x;
    const int w    = tid >> 6;           // 0..7
    const int lane = tid & 63;
    const int l15  = lane & 15;
    const int grp  = lane >> 4;
    const int row0 = blockIdx.x * 16;

    BF8 woutf[2];
    #pragma unroll
    for (int oc = 0; oc < 2; oc++) {
        const float* q = W_out + (l15 + 16*oc) * 32 + grp * 8;  // B[k=c][col=o]
        #pragma unroll
        for (int j = 0; j < 8; j++) woutf[oc].h[j] = f2bf(q[j]);
    }
    const float bo0 = b_out[l15], bo1 = b_out[16 + l15];

    for (int ntq = 0; ntq < 4; ntq++) {
        // ---- stage 2: wave owns c = w*4 + ci; acc[ci][nh] over K=128 ----
        floatx4 acc[4][2];
        #pragma unroll
        for (int ci = 0; ci < 4; ci++)
            #pragma unroll
            for (int nh = 0; nh < 2; nh++) acc[ci][nh] = (floatx4){0.f,0.f,0.f,0.f};

        #pragma unroll
        for (int ci = 0; ci < 4; ci++) {
            const int c = w*4 + ci;
            const unsigned short* yc = y + ((long)(row0 + l15) * 32 + c) * 128 + grp*8;
            const unsigned short* wb = wm16 + ((long)(c*128 + ntq*32 + l15)) * 128 + grp*8;
            #pragma unroll
            for (int kc = 0; kc < 4; kc++) {
                BF8 a;
                const uint4 av = *(const uint4*)&yc[kc*32];       // A[bt=l15][k=m]
                a.w[0] = av.x; a.w[1] = av.y; a.w[2] = av.z; a.w[3] = av.w;
                #pragma unroll
                for (int nh = 0; nh < 2; nh++) {
                    BF8 b;
                    const uint4 bv = *(const uint4*)&wb[nh*16*128 + kc*32]; // B[k=m][col=n]
                    b.w[0] = bv.x; b.w[1] = bv.y; b.w[2] = bv.z; b.w[3] = bv.w;
                    acc[ci][nh] = __builtin_amdgcn_mfma_f32_16x16x32_bf16(a.v, b.v, acc[ci][nh], 0, 0, 0);
                }
            }
        }
        // bias + pack 4 ci (c contiguous) -> wc[n][bt][c] as b64
        #pragma unroll
        for (int nh = 0; nh < 2; nh++) {
            const float bm0 = b_mods[(w*4 + 0)*128 + ntq*32 + nh*16 + l15];
            const float bm1 = b_mods[(w*4 + 1)*128 + ntq*32 + nh*16 + l15];
            const float bm2 = b_mods[(w*4 + 2)*128 + ntq*32 + nh*16 + l15];
            const float bm3 = b_mods[(w*4 + 3)*128 + ntq*32 + nh*16 + l15];
            #pragma unroll
            for (int r = 0; r < 4; r++) {
                uint2 pk;
                pk.x = (uint32_t)f2bf(acc[0][nh][r] + bm0) | ((uint32_t)f2bf(acc[1][nh][r] + bm1) << 16);
                pk.y = (uint32_t)f2bf(acc[2][nh][r] + bm2) | ((uint32_t)f2bf(acc[3][nh][r] + bm3) << 16);
                *(uint2*)&wc[(nh*16 + l15)*WP2_N + (grp*4 + r)*WP2_BT + w*4] = pk;
            }
        }
        __syncthreads();

        // ---- stage 3: wave -> 4 n rows; K = c = 32, one MFMA per (n, o-half) ----
        #pragma unroll
        for (int k = 0; k < 4; k++) {
            const int nloc = w*4 + k;
            BF8 a;
            const uint4 av = *(const uint4*)&wc[nloc*WP2_N + l15*WP2_BT + grp*8]; // A[bt][k=c]
            a.w[0] = av.x; a.w[1] = av.y; a.w[2] = av.z; a.w[3] = av.w;
            #pragma unroll
            for (int oc = 0; oc < 2; oc++) {
                floatx4 v = {0.f, 0.f, 0.f, 0.f};
                v = __builtin_amdgcn_mfma_f32_16x16x32_bf16(a.v, woutf[oc].v, v, 0, 0, 0);
                const float bo = oc ? bo1 : bo0;
                float* po = out + (long)(row0) * ODIM + (ntq*32 + nloc)*32 + oc*16 + l15;
                #pragma unroll
                for (int r = 0; r < 4; r++)
                    po[(long)(grp*4 + r) * ODIM] = v[r] + bo;   // 64-B segments
            }
        }
        __syncthreads();   // wc reused next ntq
    }
}

// ======================= fallback: round-2 fused =======================
#define BT    16
#define NTHR  1024
#define GRID  512
#define XP_BT 40
#define XP_M  656
#define YP_BT 40
#define YP_C  648
#define WP_BT 34
#define WP_N  546
#define WBUF  8736

template<bool WBF16>
__global__ __launch_bounds__(NTHR, 4)
void tinymod_fused(const float* __restrict__ x,
                   const float* __restrict__ W_in,
                   const float* __restrict__ b_in,
                   const void*  __restrict__ wmods,
                   const float* __restrict__ b_mods,
                   const float* __restrict__ W_out,
                   const float* __restrict__ b_out,
                   float* __restrict__ out)
{
    __shared__ unsigned short xs[32 * XP_M] __attribute__((aligned(16)));
    __shared__ unsigned short ys[32 * YP_C] __attribute__((aligned(16)));
    __shared__ unsigned short wc[2 * WBUF]  __attribute__((aligned(16)));

    const int tid  = threadIdx.x;
    const int w    = tid >> 6;
    const int lane = tid & 63;
    const int l15  = lane & 15;
    const int grp  = lane >> 4;
    const int row0 = blockIdx.x * BT;
    const int cc = w >> 3, mq = w & 7;

    BF8 winf;
    {
        const float* p = W_in + (l15 + 16*cc) * 32 + grp * 8;
        #pragma unroll
        for (int j = 0; j < 8; j++) winf.h[j] = f2bf(p[j]);
    }
    const float bin = b_in[l15 + 16*cc];

    const int smp = tid & 31, sbt = (tid >> 5) & 15, sih = tid >> 9;
    const float* xb = x + (row0 + sbt) * IDIM + smp + sih * (16 * 128);

    floatx4 acc[2][8];
    #pragma unroll
    for (int a = 0; a < 2; a++)
        #pragma unroll
        for (int b = 0; b < 8; b++) acc[a][b] = (floatx4){0.f, 0.f, 0.f, 0.f};

    const unsigned short* __restrict__ wm16 = (const unsigned short*)wmods;
    const float*          __restrict__ wm32 = (const float*)wmods;
    int wmb[2];
    #pragma unroll
    for (int c2 = 0; c2 < 2; c2++)
        wmb[c2] = ((2*w + c2) * 128 + l15) * 128 + grp * 8;

    float xr[16];
    #pragma unroll
    for (int j = 0; j < 16; j++) xr[j] = xb[j * 128];

    #pragma unroll
    for (int mc = 0; mc < 4; mc++) {
        #pragma unroll
        for (int p = 0; p < 2; p++) {
            BF8 t;
            #pragma unroll
            for (int j = 0; j < 8; j++) t.h[j] = f2bf(xr[p*8 + j]);
            uint4 v4; v4.x = t.w[0]; v4.y = t.w[1]; v4.z = t.w[2]; v4.w = t.w[3];
            *(uint4*)&xs[smp*XP_M + sbt*XP_BT + sih*16 + p*8] = v4;
        }
        __syncthreads();

        unsigned short yh[4][4];
        #pragma unroll
        for (int k = 0; k < 4; k++) {
            BF8 a;
            const uint4 av = *(const uint4*)&xs[(mq*4 + k)*XP_M + l15*XP_BT + grp*8];
            a.w[0] = av.x; a.w[1] = av.y; a.w[2] = av.z; a.w[3] = av.w;
            floatx4 yv = {0.f, 0.f, 0.f, 0.f};
            yv = __builtin_amdgcn_mfma_f32_16x16x32_bf16(a.v, winf.v, yv, 0, 0, 0);
            #pragma unroll
            for (int r = 0; r < 4; r++) yh[k][r] = f2bf(yv[r] + bin);
        }
        #pragma unroll
        for (int r = 0; r < 4; r++) {
            uint2 pk;
            pk.x = (uint32_t)yh[0][r] | ((uint32_t)yh[1][r] << 16);
            pk.y = (uint32_t)yh[2][r] | ((uint32_t)yh[3][r] << 16);
            *(uint2*)&ys[(l15 + 16*cc)*YP_C + (grp*4 + r)*YP_BT + mq*4] = pk;
        }
        __syncthreads();

        float xr2[16];
        if (mc < 3) {
            #pragma unroll
            for (int j = 0; j < 16; j++) xr2[j] = xb[j*128 + (mc + 1)*32];
        }

        #pragma unroll
        for (int c2 = 0; c2 < 2; c2++) {
            BF8 a;
            const uint4 av = *(const uint4*)&ys[(2*w + c2)*YP_C + l15*YP_BT + grp*8];
            a.w[0] = av.x; a.w[1] = av.y; a.w[2] = av.z; a.w[3] = av.w;
            #pragma unroll
            for (int nt = 0; nt < 8; nt++) {
                BF8 b;
                if (WBF16) {
                    const uint4 bv = *(const uint4*)&wm16[wmb[c2] + nt*2048 + mc*32];
                    b.w[0] = bv.x; b.w[1] = bv.y; b.w[2] = bv.z; b.w[3] = bv.w;
                } else {
                    const float* wp = wm32 + wmb[c2] + nt*2048 + mc*32;
                    #pragma unroll
                    for (int j = 0; j < 8; j++) b.h[j] = f2bf(wp[j]);
                }
                acc[c2][nt] = __builtin_amdgcn_mfma_f32_16x16x32_bf16(a.v, b.v, acc[c2][nt], 0, 0, 0);
            }
        }
        if (mc < 3) {
            #pragma unroll
            for (int j = 0; j < 16; j++) xr[j] = xr2[j];
        }
    }

    BF8 woutf[2];
    #pragma unroll
    for (int oc = 0; oc < 2; oc++) {
        const float* q = W_out + (l15 + 16*oc) * 32 + grp * 8;
        #pragma unroll
        for (int j = 0; j < 8; j++) woutf[oc].h[j] = f2bf(q[j]);
    }
    const float bo0 = b_out[l15], bo1 = b_out[16 + l15];
    float bm[2][8];
    #pragma unroll
    for (int c2 = 0; c2 < 2; c2++)
        #pragma unroll
        for (int nt = 0; nt < 8; nt++)
            bm[c2][nt] = b_mods[(2*w + c2)*128 + nt*16 + l15];

    float* outb = out + (long)row0 * ODIM;
    #pragma unroll
    for (int nt = 0; nt < 8; nt++) {
        const int buf = (nt & 1) * WBUF;
        #pragma unroll
        for (int r = 0; r < 4; r++) {
            const uint32_t pk = (uint32_t)f2bf(acc[0][nt][r] + bm[0][nt])
                              | ((uint32_t)f2bf(acc[1][nt][r] + bm[1][nt]) << 16);
            *(uint32_t*)&wc[buf + l15*WP_N + (grp*4 + r)*WP_BT + 2*w] = pk;
        }
        __syncthreads();
        BF8 a;
        #pragma unroll
        for (int j = 0; j < 4; j++)
            a.w[j] = *(const uint32_t*)&wc[buf + w*WP_N + l15*WP_BT + grp*8 + j*2];
        #pragma unroll
        for (int oc = 0; oc < 2; oc++) {
            floatx4 v = {0.f, 0.f, 0.f, 0.f};
            v = __builtin_amdgcn_mfma_f32_16x16x32_bf16(a.v, woutf[oc].v, v, 0, 0, 0);
            const float bo = oc ? bo1 : bo0;
            float* po = outb + (nt*16 + w)*32 + oc*16 + l15;
            #pragma unroll
            for (int r = 0; r < 4; r++)
                po[(grp*4 + r) * ODIM] = v[r] + bo;
        }
    }
}

// prologue: W_mods fp32 -> bf16 (2 MiB -> 1 MiB, L2/L3 resident)
__global__ void wmods_to_bf16(const float* __restrict__ wsrc, unsigned short* __restrict__ o) {
    const int i = (blockIdx.x * 256 + threadIdx.x) * 4;
    const float4 f = *(const float4*)(wsrc + i);
    uint2 pk;
    pk.x = (uint32_t)f2bf(f.x) | ((uint32_t)f2bf(f.y) << 16);
    pk.y = (uint32_t)f2bf(f.z) | ((uint32_t)f2bf(f.w) << 16);
    *(uint2*)(o + i) = pk;
}

extern "C" void kernel_launch(void* const* d_in, const int* in_sizes, int n_in,
                              void* d_out, int out_size, void* d_ws, size_t ws_size,
                              hipStream_t stream)
{
    const float* x     = (const float*)d_in[0];
    const float* W_in  = (const float*)d_in[1];
    const float* b_in  = (const float*)d_in[2];
    const float* Wm    = (const float*)d_in[3];
    const float* b_m   = (const float*)d_in[4];
    const float* W_out = (const float*)d_in[5];
    const float* b_out = (const float*)d_in[6];
    float* out = (float*)d_out;

    const size_t wm_bytes = 32u * 128u * 128u * sizeof(unsigned short);   // 1 MiB
    const size_t y_bytes  = (size_t)8192 * 32 * 128 * sizeof(unsigned short); // 64 MiB

    if (ws_size >= wm_bytes + y_bytes) {
        unsigned short* wbf = (unsigned short*)d_ws;
        unsigned short* y   = (unsigned short*)((char*)d_ws + wm_bytes);
        wmods_to_bf16<<<512, 256, 0, stream>>>(Wm, wbf);
        k1_fcin<<<512, 512, 0, stream>>>(x, W_in, b_in, y);
        k2_mods_out<<<512, 512, 0, stream>>>(y, wbf, b_m, W_out, b_out, out);
    } else if (ws_size >= wm_bytes) {
        unsigned short* wbf = (unsigned short*)d_ws;
        wmods_to_bf16<<<512, 256, 0, stream>>>(Wm, wbf);
        tinymod_fused<true><<<GRID, NTHR, 0, stream>>>(x, W_in, b_in, (const void*)wbf,
                                                       b_m, W_out, b_out, out);
    } else {
        tinymod_fused<false><<<GRID, NTHR, 0, stream>>>(x, W_in, b_in, (const void*)Wm,
                                                        b_m, W_out, b_out, out);
    }
}